// Round 16
// baseline (137.516 us; speedup 1.0000x reference)
//
#include <hip/hip_runtime.h>
#include <hip/hip_bf16.h>
#include <stdint.h>

#define SEQ   2048
#define HID   2048
#define NQH   32
#define NKVH  8
#define COMP  1024

using bf16x8 = __attribute__((ext_vector_type(8))) __bf16;
using f32x4  = __attribute__((ext_vector_type(4))) float;

// XOR swizzle for 128B LDS row-chunks
#define SW(row, off) ((off) ^ (((row) & 7) << 4))

union BF8 { bf16x8 v; __bf16 e[8]; };

typedef __attribute__((address_space(1))) const void GAS;
typedef __attribute__((address_space(3))) void LAS;
// offset immediate ALWAYS 0 (R6 lesson: inst offset shifts the LDS dest too)
__device__ __forceinline__ void gl16(const void* g, void* l) {
    __builtin_amdgcn_global_load_lds((GAS*)g, (LAS*)l, 16, 0, 0);
}

// =====================================================================
// Pre-pass: gather+split to packed hi/lo layout (R10-proven).
// =====================================================================
__global__ __launch_bounds__(256)
void k_split(const int* __restrict__ ids, const float* __restrict__ tab,
             const float* __restrict__ wq, const float* __restrict__ wk,
             char* __restrict__ xp, char* __restrict__ wp) {
    const int b = blockIdx.x;
    const int half = threadIdx.x >> 7;
    const int t = threadIdx.x & 127;
    const float* src;
    char* dbase;
    if (b < 1024) {
        int row = b * 2 + half;
        src = tab + (size_t)ids[row] * HID;
        dbase = xp + (size_t)row * 8192;
    } else {
        int row = (b - 1024) * 2 + half;
        src = (row < 2048) ? wq + (size_t)row * HID : wk + (size_t)(row - 2048) * HID;
        dbase = wp + (size_t)row * 8192;
    }
    const int c0 = t * 16;
    float f[16];
    #pragma unroll
    for (int u = 0; u < 4; ++u)
        *(float4*)(f + 4 * u) = *(const float4*)(src + c0 + 4 * u);
    BF8 H0, L0, H1, L1;
    #pragma unroll
    for (int e = 0; e < 8; ++e) {
        H0.e[e] = (__bf16)f[e];
        L0.e[e] = (__bf16)(f[e] - (float)H0.e[e]);
        H1.e[e] = (__bf16)f[e + 8];
        L1.e[e] = (__bf16)(f[e + 8] - (float)H1.e[e]);
    }
    char* d = dbase + (t >> 2) * 256 + (t & 3) * 32;
    *(bf16x8*)(d)       = H0.v;  *(bf16x8*)(d + 16)  = H1.v;
    *(bf16x8*)(d + 128) = L0.v;  *(bf16x8*)(d + 144) = L1.v;
}

// =====================================================================
// GEMM: C[2048][2560] over K=2048, 3-term bf16 split MFMA.
// R5-proven 128x64 tile, BK=64, 4 waves (2x2, 64x32 each), 48KB LDS,
// 3 blocks/CU. Grid 640 — ALL blocks co-resident (perfect packing).
// XCD cluster: 8m x 10n per XCD (R15-proven mechanism; per-step active
// set ~416KB, L2-fit). Per-element MFMA k-chain order identical to R15
// -> qf/kf/ksumP bit-identical.
// =====================================================================
__global__ __launch_bounds__(256, 3)
void k_gemm(const char* __restrict__ xp, const char* __restrict__ wp,
            const float* __restrict__ cosd, const float* __restrict__ sind,
            float* __restrict__ qf, float* __restrict__ kf,
            float* __restrict__ ksumP) {
    __shared__ __align__(16) char lds[49152];
    char* AH = lds;              // [128 rows][128B] (16KB)
    char* AL = lds + 16384;      // (16KB)
    char* BH = lds + 32768;      // [64 rows][128B] (8KB)
    char* BL = lds + 40960;      // (8KB)
    float* Ct = (float*)lds;     // epilogue reuse: [128][68] f32 (34.8KB)

    const int bid = blockIdx.x;                 // 640 = 8 XCD x 80
    const int x = bid & 7, loc = bid >> 3;      // XCD id, local 0..79
    const int m_blk = (x & 1) * 8 + (loc & 7);  // 0..15
    const int n_blk = (x >> 1) * 10 + (loc >> 3); // 0..39
    const int m0 = m_blk * 128, n0 = n_blk * 64;

    const int tid = threadIdx.x;
    const int L = tid & 63, q4 = L >> 4;
    const int w = tid >> 6, wr = w >> 1, wc = w & 1;

    const int rl = L >> 3;
    const int so = ((L & 7) * 16) ^ (rl << 4);
    const char *ap[4], *bp[2];
    #pragma unroll
    for (int t = 0; t < 4; ++t) {
        int r = w * 32 + t * 8 + rl;
        ap[t] = xp + (size_t)(m0 + r) * 8192 + so;
    }
    #pragma unroll
    for (int t = 0; t < 2; ++t) {
        int r = w * 16 + t * 8 + rl;
        bp[t] = wp + (size_t)(n0 + r) * 8192 + so;
    }

    f32x4 acc[4][2];
    #pragma unroll
    for (int i = 0; i < 4; ++i)
        #pragma unroll
        for (int j = 0; j < 2; ++j) acc[i][j] = (f32x4){0.f, 0.f, 0.f, 0.f};

    for (int ks = 0; ks < 32; ++ks) {
        #pragma unroll
        for (int t = 0; t < 4; ++t) {
            int ldso = (w * 32 + t * 8) * 128;
            gl16(ap[t],       AH + ldso);
            gl16(ap[t] + 128, AL + ldso);
            ap[t] += 256;
        }
        #pragma unroll
        for (int t = 0; t < 2; ++t) {
            int ldso = (w * 16 + t * 8) * 128;
            gl16(bp[t],       BH + ldso);
            gl16(bp[t] + 128, BL + ldso);
            bp[t] += 256;
        }
        __syncthreads();
        bf16x8 bh[2][2], bl[2][2];
        #pragma unroll
        for (int nt = 0; nt < 2; ++nt) {
            int jn = wc * 32 + nt * 16 + (L & 15);
            #pragma unroll
            for (int m = 0; m < 2; ++m) {
                int off = SW(jn, m * 64 + q4 * 16);
                bh[nt][m] = *(const bf16x8*)(BH + jn * 128 + off);
                bl[nt][m] = *(const bf16x8*)(BL + jn * 128 + off);
            }
        }
        #pragma unroll
        for (int mt = 0; mt < 4; ++mt) {
            int rm = wr * 64 + mt * 16 + (L & 15);
            int o0 = SW(rm, q4 * 16), o1 = SW(rm, 64 + q4 * 16);
            bf16x8 ah0 = *(const bf16x8*)(AH + rm * 128 + o0);
            bf16x8 ah1 = *(const bf16x8*)(AH + rm * 128 + o1);
            bf16x8 al0 = *(const bf16x8*)(AL + rm * 128 + o0);
            bf16x8 al1 = *(const bf16x8*)(AL + rm * 128 + o1);
            #pragma unroll
            for (int nt = 0; nt < 2; ++nt) {
                f32x4 a = acc[mt][nt];
                a = __builtin_amdgcn_mfma_f32_16x16x32_bf16(ah0, bh[nt][0], a, 0, 0, 0);
                a = __builtin_amdgcn_mfma_f32_16x16x32_bf16(ah1, bh[nt][1], a, 0, 0, 0);
                a = __builtin_amdgcn_mfma_f32_16x16x32_bf16(ah0, bl[nt][0], a, 0, 0, 0);
                a = __builtin_amdgcn_mfma_f32_16x16x32_bf16(ah1, bl[nt][1], a, 0, 0, 0);
                a = __builtin_amdgcn_mfma_f32_16x16x32_bf16(al0, bh[nt][0], a, 0, 0, 0);
                a = __builtin_amdgcn_mfma_f32_16x16x32_bf16(al1, bh[nt][1], a, 0, 0, 0);
                acc[mt][nt] = a;
            }
        }
        __syncthreads();
    }

    #pragma unroll
    for (int mt = 0; mt < 4; ++mt)
        #pragma unroll
        for (int nt = 0; nt < 2; ++nt)
            #pragma unroll
            for (int r = 0; r < 4; ++r)
                Ct[(wr * 64 + mt * 16 + q4 * 4 + r) * 68 + wc * 32 + nt * 16 + (L & 15)] =
                    acc[mt][nt][r];
    __syncthreads();

    // ---- RoPE + f32 store (one head-column tile) ----
    const bool isK = (n0 >= 2048);
    const int head = (isK ? n0 - 2048 : n0) >> 6;
    float* dst0 = (isK ? kf : qf) + (size_t)head * SEQ * 64;
    for (int s = 0; s < 16; ++s) {
        int pi = tid + s * 256;
        int r = pi >> 5, d = pi & 31;
        int i = m0 + r;
        float x0 = Ct[r * 68 + d], x1 = Ct[r * 68 + d + 32];
        float c0 = cosd[i * 64 + d], c1 = cosd[i * 64 + d + 32];
        float s0 = sind[i * 64 + d], s1 = sind[i * 64 + d + 32];
        float o0 = x0 * c0 - x1 * s0;
        float o1 = x1 * c1 + x0 * s1;
        float* dst = dst0 + (size_t)i * 64;
        dst[d] = o0; dst[d + 32] = o1;
        if (isK) { Ct[r * 68 + d] = o0; Ct[r * 68 + d + 32] = o1; }
    }
    if (isK) {
        __syncthreads();
        if (tid < 64) {
            float ssum = 0.f;
            for (int r = 0; r < 128; ++r) ssum += Ct[r * 68 + tid];
            ksumP[m_blk * 512 + head * 64 + tid] = ssum;
        }
    }
}

// =====================================================================
// Per-group weighted moments (R10-proven LDS version).
// =====================================================================
__global__ __launch_bounds__(256)
void k_moments(const float* __restrict__ qf, const float* __restrict__ ksumP,
               float* __restrict__ Ap, float* __restrict__ Gp) {
    __shared__ float qs[256][68];
    __shared__ float ws[256];
    __shared__ float ks[64];
    const int b = blockIdx.x, g = b >> 5, chunk = b & 31;
    const int t = threadIdx.x;
    const int head = g * 4 + (chunk >> 3);
    const int i0 = (chunk & 7) * 256;

    const float* src = qf + ((size_t)head * SEQ + i0) * 64;
    #pragma unroll
    for (int s = 0; s < 16; ++s) {
        int idx = s * 1024 + t * 4;
        float4 v = *(const float4*)(src + idx);
        *(float4*)(&qs[idx >> 6][idx & 63]) = v;
    }
    if (t < 64) {
        float s = 0.f;
        #pragma unroll
        for (int mb = 0; mb < 16; ++mb) s += ksumP[mb * 512 + g * 64 + t];
        ks[t] = s;
    }
    __syncthreads();

    float dot = 0.f;
    #pragma unroll
    for (int u = 0; u < 16; ++u) {
        float4 a = *(const float4*)(&qs[t][4 * u]);
        float4 kk = *(const float4*)(&ks[4 * u]);
        dot += a.x * kk.x + a.y * kk.y + a.z * kk.z + a.w * kk.w;
    }
    ws[t] = 1.0f / (2048.0f + dot);
    __syncthreads();

    const int wv = t >> 6, l = t & 63;
    float ga[16];
    #pragma unroll
    for (int u = 0; u < 16; ++u) ga[u] = 0.f;
    float aa = 0.f;
    for (int r = 0; r < 256; ++r) {
        float qa = qs[r][l];
        float wr = ws[r];
        float wq = wr * qa;
        aa = fmaf(wr, qa, aa);
        float4 b0 = *(const float4*)(&qs[r][wv * 16]);
        float4 b1 = *(const float4*)(&qs[r][wv * 16 + 4]);
        float4 b2 = *(const float4*)(&qs[r][wv * 16 + 8]);
        float4 b3 = *(const float4*)(&qs[r][wv * 16 + 12]);
        ga[0]  = fmaf(wq, b0.x, ga[0]);  ga[1]  = fmaf(wq, b0.y, ga[1]);
        ga[2]  = fmaf(wq, b0.z, ga[2]);  ga[3]  = fmaf(wq, b0.w, ga[3]);
        ga[4]  = fmaf(wq, b1.x, ga[4]);  ga[5]  = fmaf(wq, b1.y, ga[5]);
        ga[6]  = fmaf(wq, b1.z, ga[6]);  ga[7]  = fmaf(wq, b1.w, ga[7]);
        ga[8]  = fmaf(wq, b2.x, ga[8]);  ga[9]  = fmaf(wq, b2.y, ga[9]);
        ga[10] = fmaf(wq, b2.z, ga[10]); ga[11] = fmaf(wq, b2.w, ga[11]);
        ga[12] = fmaf(wq, b3.x, ga[12]); ga[13] = fmaf(wq, b3.y, ga[13]);
        ga[14] = fmaf(wq, b3.z, ga[14]); ga[15] = fmaf(wq, b3.w, ga[15]);
    }
    float* gdst = Gp + (size_t)b * 4096 + l * 64 + wv * 16;
    #pragma unroll
    for (int u = 0; u < 16; ++u) gdst[u] = ga[u];
    if (wv == 0) Ap[b * 64 + l] = aa;
}

// ---- reduce Gp/Ap over the 32 chunks (R8-proven; c-order identical
//      to R15's in-eval reduction -> bit-identical Gs/As) ----
__global__ __launch_bounds__(256)
void k_gsum(const float* __restrict__ Gp, const float* __restrict__ Ap,
            float* __restrict__ Gs, float* __restrict__ As) {
    const int b = blockIdx.x;          // 128 = 8 g x 16 parts
    const int g = b >> 4, part = b & 15;
    const int e = part * 256 + threadIdx.x;
    float s = 0.f;
    for (int c = 0; c < 32; ++c) s += Gp[(size_t)(g * 32 + c) * 4096 + e];
    Gs[g * 4096 + e] = s;
    if (part == 0 && threadIdx.x < 64) {
        float sa = 0.f;
        for (int c = 0; c < 32; ++c) sa += Ap[(g * 32 + c) * 64 + threadIdx.x];
        As[g * 64 + threadIdx.x] = sa;
    }
}

// =====================================================================
// eval: pimp[g][j] = A.k + 0.5 k^T G k. Loads pre-reduced Gs/As (4MB
// total re-read instead of 128MB). d-sliced body (R10-proven).
// =====================================================================
__global__ __launch_bounds__(256)
void k_eval(const float* __restrict__ kf, const float* __restrict__ As,
            const float* __restrict__ Gs, float* __restrict__ pimp) {
    __shared__ float G[4096];
    __shared__ float A[64];
    __shared__ float part[4][64];
    const int b = blockIdx.x, g = b >> 5, jc = b & 31;
    const int t = threadIdx.x;
    #pragma unroll
    for (int s4 = 0; s4 < 4; ++s4) {
        const int e = s4 * 1024 + t * 4;
        *(float4*)(G + e) = *(const float4*)(Gs + (size_t)g * 4096 + e);
    }
    if (t < 64) A[t] = As[g * 64 + t];
    __syncthreads();

    const int l = t & 63, wv = t >> 6;
    const int j = jc * 64 + l;
    const float* krow = kf + ((size_t)g * SEQ + j) * 64;
    float k[64];
    #pragma unroll
    for (int u = 0; u < 16; ++u) *(float4*)(k + 4 * u) = *(const float4*)(krow + 4 * u);

    float acc = 0.f;
    #pragma unroll
    for (int dd = 0; dd < 16; ++dd) {
        int d = wv * 16 + dd;
        const float* Gr = G + d * 64;
        float tmp = 0.f;
        #pragma unroll
        for (int dp = 0; dp < 64; dp += 4) {
            float4 gv = *(const float4*)(Gr + dp);
            tmp = fmaf(gv.x, k[dp],     tmp);
            tmp = fmaf(gv.y, k[dp + 1], tmp);
            tmp = fmaf(gv.z, k[dp + 2], tmp);
            tmp = fmaf(gv.w, k[dp + 3], tmp);
        }
        acc = fmaf(k[d], A[d] + 0.5f * tmp, acc);
    }
    part[wv][l] = acc;
    __syncthreads();
    if (t < 64) {
        float s = ((part[0][t] + part[1][t]) + part[2][t]) + part[3][t];
        pimp[g * SEQ + jc * 64 + t] = s;
    }
}

// ---- rank: f64 group-sum inline (g-ascending), exact top-k,
//      R15-proven 256-block geometry ----
__global__ __launch_bounds__(256)
void k_rank(const float* __restrict__ pimp, int* __restrict__ sel) {
    __shared__ double v[SEQ];
    for (int j = threadIdx.x; j < SEQ; j += 256) {
        double s = 0.0;
        #pragma unroll
        for (int g = 0; g < 8; ++g) s += (double)pimp[g * SEQ + j];
        v[j] = s;
    }
    __syncthreads();
    const int grp = threadIdx.x >> 5, lane32 = threadIdx.x & 31;
    const int j = blockIdx.x * 8 + grp;
    double vj = v[j];
    int rank = 0;
    #pragma unroll 8
    for (int i = 0; i < 64; ++i) {
        int j2 = i * 32 + lane32;
        double u = v[j2];
        rank += (u > vj || (u == vj && j2 < j)) ? 1 : 0;
    }
    #pragma unroll
    for (int off = 16; off; off >>= 1) rank += __shfl_xor(rank, off, 32);
    if (lane32 == 0) sel[j] = (rank < COMP) ? 1 : 0;
}

// ---- compact + last-slot override + gather ids ----
__global__ __launch_bounds__(256)
void k_out(const int* __restrict__ sel, const int* __restrict__ ids, int* __restrict__ out) {
    __shared__ int s[SEQ];
    __shared__ int part[256];
    int t = threadIdx.x;
    for (int j = t; j < SEQ; j += 256) s[j] = sel[j];
    __syncthreads();
    int base = t * 8, cnt = 0;
    #pragma unroll
    for (int r = 0; r < 8; ++r) cnt += s[base + r];
    part[t] = cnt;
    __syncthreads();
    if (t == 0) {
        int run = 0;
        for (int i2 = 0; i2 < 256; ++i2) { int tmp = part[i2]; part[i2] = run; run += tmp; }
    }
    __syncthreads();
    int pos = part[t];
    for (int r = 0; r < 8; ++r) {
        int j = base + r;
        if (s[j]) {
            int idx = (pos == COMP - 1) ? (SEQ - 1) : j;
            out[COMP + pos] = idx;
            out[pos] = ids[idx];
            pos++;
        }
    }
}

extern "C" void kernel_launch(void* const* d_in, const int* in_sizes, int n_in,
                              void* d_out, int out_size, void* d_ws, size_t ws_size,
                              hipStream_t stream) {
    const int*   ids = (const int*)d_in[0];
    const float* tab = (const float*)d_in[1];
    const float* wq  = (const float*)d_in[2];
    const float* wk  = (const float*)d_in[3];
    const float* ct  = (const float*)d_in[4];
    const float* st  = (const float*)d_in[5];
    int* out = (int*)d_out;
    char* ws = (char*)d_ws;

    const size_t MB = 1 << 20;
    char*  xp    = ws;                                   // 16 MB packed x hi/lo
    char*  wp    = ws + 16 * MB;                         // 20 MB packed W hi/lo
    float* qf    = (float*)(ws + 36 * MB);               // 16 MB [32][2048][64]
    float* kf    = (float*)(ws + 52 * MB);               //  4 MB [8][2048][64]
    float* ksumP = (float*)(ws + 56 * MB);               // 32 KB
    float* Gp    = (float*)(ws + 56 * MB + 0x10000);     //  4 MB [8][32][4096]
    float* Ap    = (float*)(ws + 60 * MB + 0x10000);     // 64 KB
    float* Gs    = (float*)(ws + 60 * MB + 0x20000);     // 128 KB [8][4096]
    float* As    = (float*)(ws + 60 * MB + 0x40000);     //  2 KB
    float* pimp  = (float*)(ws + 60 * MB + 0x50000);     // 64 KB [8][2048]
    int*   sel   = (int*)(ws + 60 * MB + 0x60000);       //  8 KB

    k_split<<<2304, 256, 0, stream>>>(ids, tab, wq, wk, xp, wp);
    k_gemm<<<640, 256, 0, stream>>>(xp, wp, ct, st, qf, kf, ksumP);
    k_moments<<<256, 256, 0, stream>>>(qf, ksumP, Ap, Gp);
    k_gsum<<<128, 256, 0, stream>>>(Gp, Ap, Gs, As);
    k_eval<<<256, 256, 0, stream>>>(kf, As, Gs, pimp);
    k_rank<<<256, 256, 0, stream>>>(pimp, sel);
    k_out<<<1, 256, 0, stream>>>(sel, ids, out);
}

// Round 17
// 131.904 us; speedup vs baseline: 1.0425x; 1.0425x over previous
//
#include <hip/hip_runtime.h>
#include <hip/hip_bf16.h>
#include <stdint.h>

#define SEQ   2048
#define HID   2048
#define NQH   32
#define NKVH  8
#define COMP  1024

using bf16x8 = __attribute__((ext_vector_type(8))) __bf16;
using f32x4  = __attribute__((ext_vector_type(4))) float;

// XOR swizzle for 128B LDS row-chunks
#define SW(row, off) ((off) ^ (((row) & 7) << 4))

union BF8 { bf16x8 v; __bf16 e[8]; };

typedef __attribute__((address_space(1))) const void GAS;
typedef __attribute__((address_space(3))) void LAS;
// offset immediate ALWAYS 0 (R6 lesson: inst offset shifts the LDS dest too)
__device__ __forceinline__ void gl16(const void* g, void* l) {
    __builtin_amdgcn_global_load_lds((GAS*)g, (LAS*)l, 16, 0, 0);
}

// =====================================================================
// Pre-pass: gather+split to packed hi/lo layout (R10-proven).
// =====================================================================
__global__ __launch_bounds__(256)
void k_split(const int* __restrict__ ids, const float* __restrict__ tab,
             const float* __restrict__ wq, const float* __restrict__ wk,
             char* __restrict__ xp, char* __restrict__ wp) {
    const int b = blockIdx.x;
    const int half = threadIdx.x >> 7;
    const int t = threadIdx.x & 127;
    const float* src;
    char* dbase;
    if (b < 1024) {
        int row = b * 2 + half;
        src = tab + (size_t)ids[row] * HID;
        dbase = xp + (size_t)row * 8192;
    } else {
        int row = (b - 1024) * 2 + half;
        src = (row < 2048) ? wq + (size_t)row * HID : wk + (size_t)(row - 2048) * HID;
        dbase = wp + (size_t)row * 8192;
    }
    const int c0 = t * 16;
    float f[16];
    #pragma unroll
    for (int u = 0; u < 4; ++u)
        *(float4*)(f + 4 * u) = *(const float4*)(src + c0 + 4 * u);
    BF8 H0, L0, H1, L1;
    #pragma unroll
    for (int e = 0; e < 8; ++e) {
        H0.e[e] = (__bf16)f[e];
        L0.e[e] = (__bf16)(f[e] - (float)H0.e[e]);
        H1.e[e] = (__bf16)f[e + 8];
        L1.e[e] = (__bf16)(f[e + 8] - (float)H1.e[e]);
    }
    char* d = dbase + (t >> 2) * 256 + (t & 3) * 32;
    *(bf16x8*)(d)       = H0.v;  *(bf16x8*)(d + 16)  = H1.v;
    *(bf16x8*)(d + 128) = L0.v;  *(bf16x8*)(d + 144) = L1.v;
}

// =====================================================================
// GEMM: C[M=2048][N=2560] over K=2048, 3-term bf16 split MFMA.
// Tile 128x128, BK=64, 4 waves. global_load_lds staging. XCD cluster
// remap (R15-proven: 8m x 5n per XCD, ~13MB concurrent footprint).
// BYTE-IDENTICAL to R15's k_gemm.
// =====================================================================
__global__ __launch_bounds__(256, 2)
void k_gemm(const char* __restrict__ xp, const char* __restrict__ wp,
            const float* __restrict__ cosd, const float* __restrict__ sind,
            float* __restrict__ qf, float* __restrict__ kf,
            float* __restrict__ ksumP) {
    __shared__ __align__(16) char lds[67584];
    char* AH = lds;
    char* AL = lds + 16384;
    char* BH = lds + 32768;
    char* BL = lds + 49152;
    float* Ct = (float*)lds;

    const int bid = blockIdx.x;                 // 320 blocks = 8 XCD x 40
    const int x = bid & 7, loc = bid >> 3;      // XCD id, local id 0..39
    const int m_blk = (x & 1) * 8 + (loc & 7);  // 8m x 5n cluster per XCD
    const int n_blk = (x >> 1) * 5 + (loc >> 3);
    const int m0 = m_blk * 128, n0 = n_blk * 128;

    const int tid = threadIdx.x;
    const int L = tid & 63, q4 = L >> 4;
    const int w = tid >> 6, wr = w >> 1, wc = w & 1;

    const int rl = L >> 3;
    const int so = ((L & 7) * 16) ^ (rl << 4);
    const char *ap[4], *bp[4];
    #pragma unroll
    for (int t = 0; t < 4; ++t) {
        int r = w * 32 + t * 8 + rl;
        ap[t] = xp + (size_t)(m0 + r) * 8192 + so;
        bp[t] = wp + (size_t)(n0 + r) * 8192 + so;
    }

    f32x4 acc[4][4];
    #pragma unroll
    for (int i = 0; i < 4; ++i)
        #pragma unroll
        for (int j = 0; j < 4; ++j) acc[i][j] = (f32x4){0.f, 0.f, 0.f, 0.f};

    for (int ks = 0; ks < 32; ++ks) {
        #pragma unroll
        for (int t = 0; t < 4; ++t) {
            int ldso = (w * 32 + t * 8) * 128;
            gl16(ap[t],       AH + ldso);
            gl16(ap[t] + 128, AL + ldso);
            gl16(bp[t],       BH + ldso);
            gl16(bp[t] + 128, BL + ldso);
            ap[t] += 256; bp[t] += 256;
        }
        __syncthreads();
        bf16x8 bh[4][2], bl[4][2];
        #pragma unroll
        for (int nt = 0; nt < 4; ++nt) {
            int jn = wc * 64 + nt * 16 + (L & 15);
            #pragma unroll
            for (int m = 0; m < 2; ++m) {
                int off = SW(jn, m * 64 + q4 * 16);
                bh[nt][m] = *(const bf16x8*)(BH + jn * 128 + off);
                bl[nt][m] = *(const bf16x8*)(BL + jn * 128 + off);
            }
        }
        #pragma unroll
        for (int mt = 0; mt < 4; ++mt) {
            int rm = wr * 64 + mt * 16 + (L & 15);
            int o0 = SW(rm, q4 * 16), o1 = SW(rm, 64 + q4 * 16);
            bf16x8 ah0 = *(const bf16x8*)(AH + rm * 128 + o0);
            bf16x8 ah1 = *(const bf16x8*)(AH + rm * 128 + o1);
            bf16x8 al0 = *(const bf16x8*)(AL + rm * 128 + o0);
            bf16x8 al1 = *(const bf16x8*)(AL + rm * 128 + o1);
            #pragma unroll
            for (int nt = 0; nt < 4; ++nt) {
                f32x4 a = acc[mt][nt];
                a = __builtin_amdgcn_mfma_f32_16x16x32_bf16(ah0, bh[nt][0], a, 0, 0, 0);
                a = __builtin_amdgcn_mfma_f32_16x16x32_bf16(ah1, bh[nt][1], a, 0, 0, 0);
                a = __builtin_amdgcn_mfma_f32_16x16x32_bf16(ah0, bl[nt][0], a, 0, 0, 0);
                a = __builtin_amdgcn_mfma_f32_16x16x32_bf16(ah1, bl[nt][1], a, 0, 0, 0);
                a = __builtin_amdgcn_mfma_f32_16x16x32_bf16(al0, bh[nt][0], a, 0, 0, 0);
                a = __builtin_amdgcn_mfma_f32_16x16x32_bf16(al1, bh[nt][1], a, 0, 0, 0);
                acc[mt][nt] = a;
            }
        }
        __syncthreads();
    }

    #pragma unroll
    for (int mt = 0; mt < 4; ++mt)
        #pragma unroll
        for (int nt = 0; nt < 4; ++nt)
            #pragma unroll
            for (int r = 0; r < 4; ++r)
                Ct[(wr * 64 + mt * 16 + q4 * 4 + r) * 132 + wc * 64 + nt * 16 + (L & 15)] =
                    acc[mt][nt][r];
    __syncthreads();

    const bool isK = (n0 >= 2048);
    const int hb = (isK ? n0 - 2048 : n0) >> 6;
    float* dst0 = (isK ? kf : qf) + (size_t)hb * SEQ * 64;
    for (int s = 0; s < 32; ++s) {
        int pi = s * 256 + tid;
        int row = pi >> 6, hh = (pi >> 5) & 1, d = pi & 31;
        int i = m0 + row;
        float x0 = Ct[row * 132 + hh * 64 + d];
        float x1 = Ct[row * 132 + hh * 64 + d + 32];
        float c0 = cosd[i * 64 + d], c1 = cosd[i * 64 + d + 32];
        float s0 = sind[i * 64 + d], s1 = sind[i * 64 + d + 32];
        float o0 = x0 * c0 - x1 * s0;
        float o1 = x1 * c1 + x0 * s1;
        float* dst = dst0 + (size_t)hh * SEQ * 64 + (size_t)i * 64;
        dst[d] = o0; dst[d + 32] = o1;
        if (isK) {
            Ct[row * 132 + hh * 64 + d] = o0;
            Ct[row * 132 + hh * 64 + d + 32] = o1;
        }
    }
    if (isK) {
        __syncthreads();
        if (tid < 128) {
            float ssum = 0.f;
            for (int r = 0; r < 128; ++r) ssum += Ct[r * 132 + tid];
            ksumP[m_blk * 512 + (n0 - 2048) + tid] = ssum;
        }
    }
}

// =====================================================================
// Per-group weighted moments (R10-proven LDS version, unchanged).
// =====================================================================
__global__ __launch_bounds__(256)
void k_moments(const float* __restrict__ qf, const float* __restrict__ ksumP,
               float* __restrict__ Ap, float* __restrict__ Gp) {
    __shared__ float qs[256][68];
    __shared__ float ws[256];
    __shared__ float ks[64];
    const int b = blockIdx.x, g = b >> 5, chunk = b & 31;
    const int t = threadIdx.x;
    const int head = g * 4 + (chunk >> 3);
    const int i0 = (chunk & 7) * 256;

    const float* src = qf + ((size_t)head * SEQ + i0) * 64;
    #pragma unroll
    for (int s = 0; s < 16; ++s) {
        int idx = s * 1024 + t * 4;
        float4 v = *(const float4*)(src + idx);
        *(float4*)(&qs[idx >> 6][idx & 63]) = v;
    }
    if (t < 64) {
        float s = 0.f;
        #pragma unroll
        for (int mb = 0; mb < 16; ++mb) s += ksumP[mb * 512 + g * 64 + t];
        ks[t] = s;
    }
    __syncthreads();

    float dot = 0.f;
    #pragma unroll
    for (int u = 0; u < 16; ++u) {
        float4 a = *(const float4*)(&qs[t][4 * u]);
        float4 kk = *(const float4*)(&ks[4 * u]);
        dot += a.x * kk.x + a.y * kk.y + a.z * kk.z + a.w * kk.w;
    }
    ws[t] = 1.0f / (2048.0f + dot);
    __syncthreads();

    const int wv = t >> 6, l = t & 63;
    float ga[16];
    #pragma unroll
    for (int u = 0; u < 16; ++u) ga[u] = 0.f;
    float aa = 0.f;
    for (int r = 0; r < 256; ++r) {
        float qa = qs[r][l];
        float wr = ws[r];
        float wq = wr * qa;
        aa = fmaf(wr, qa, aa);
        float4 b0 = *(const float4*)(&qs[r][wv * 16]);
        float4 b1 = *(const float4*)(&qs[r][wv * 16 + 4]);
        float4 b2 = *(const float4*)(&qs[r][wv * 16 + 8]);
        float4 b3 = *(const float4*)(&qs[r][wv * 16 + 12]);
        ga[0]  = fmaf(wq, b0.x, ga[0]);  ga[1]  = fmaf(wq, b0.y, ga[1]);
        ga[2]  = fmaf(wq, b0.z, ga[2]);  ga[3]  = fmaf(wq, b0.w, ga[3]);
        ga[4]  = fmaf(wq, b1.x, ga[4]);  ga[5]  = fmaf(wq, b1.y, ga[5]);
        ga[6]  = fmaf(wq, b1.z, ga[6]);  ga[7]  = fmaf(wq, b1.w, ga[7]);
        ga[8]  = fmaf(wq, b2.x, ga[8]);  ga[9]  = fmaf(wq, b2.y, ga[9]);
        ga[10] = fmaf(wq, b2.z, ga[10]); ga[11] = fmaf(wq, b2.w, ga[11]);
        ga[12] = fmaf(wq, b3.x, ga[12]); ga[13] = fmaf(wq, b3.y, ga[13]);
        ga[14] = fmaf(wq, b3.z, ga[14]); ga[15] = fmaf(wq, b3.w, ga[15]);
    }
    float* gdst = Gp + (size_t)b * 4096 + l * 64 + wv * 16;
    #pragma unroll
    for (int u = 0; u < 16; ++u) gdst[u] = ga[u];
    if (wv == 0) Ap[b * 64 + l] = aa;
}

// ---- reduce Gp/Ap over the 32 chunks (R16-proven; c-order identical
//      to R15's in-eval reduction -> bit-identical Gs/As) ----
__global__ __launch_bounds__(256)
void k_gsum(const float* __restrict__ Gp, const float* __restrict__ Ap,
            float* __restrict__ Gs, float* __restrict__ As) {
    const int b = blockIdx.x;          // 128 = 8 g x 16 parts
    const int g = b >> 4, part = b & 15;
    const int e = part * 256 + threadIdx.x;
    float s = 0.f;
    for (int c = 0; c < 32; ++c) s += Gp[(size_t)(g * 32 + c) * 4096 + e];
    Gs[g * 4096 + e] = s;
    if (part == 0 && threadIdx.x < 64) {
        float sa = 0.f;
        for (int c = 0; c < 32; ++c) sa += Ap[(g * 32 + c) * 64 + threadIdx.x];
        As[g * 64 + threadIdx.x] = sa;
    }
}

// =====================================================================
// eval: pimp[g][j] = A.k + 0.5 k^T G k. Loads pre-reduced Gs/As
// (R16-proven body; 4MB aggregate read instead of 128MB).
// =====================================================================
__global__ __launch_bounds__(256)
void k_eval(const float* __restrict__ kf, const float* __restrict__ As,
            const float* __restrict__ Gs, float* __restrict__ pimp) {
    __shared__ float G[4096];
    __shared__ float A[64];
    __shared__ float part[4][64];
    const int b = blockIdx.x, g = b >> 5, jc = b & 31;
    const int t = threadIdx.x;
    #pragma unroll
    for (int s4 = 0; s4 < 4; ++s4) {
        const int e = s4 * 1024 + t * 4;
        *(float4*)(G + e) = *(const float4*)(Gs + (size_t)g * 4096 + e);
    }
    if (t < 64) A[t] = As[g * 64 + t];
    __syncthreads();

    const int l = t & 63, wv = t >> 6;
    const int j = jc * 64 + l;
    const float* krow = kf + ((size_t)g * SEQ + j) * 64;
    float k[64];
    #pragma unroll
    for (int u = 0; u < 16; ++u) *(float4*)(k + 4 * u) = *(const float4*)(krow + 4 * u);

    float acc = 0.f;
    #pragma unroll
    for (int dd = 0; dd < 16; ++dd) {
        int d = wv * 16 + dd;
        const float* Gr = G + d * 64;
        float tmp = 0.f;
        #pragma unroll
        for (int dp = 0; dp < 64; dp += 4) {
            float4 gv = *(const float4*)(Gr + dp);
            tmp = fmaf(gv.x, k[dp],     tmp);
            tmp = fmaf(gv.y, k[dp + 1], tmp);
            tmp = fmaf(gv.z, k[dp + 2], tmp);
            tmp = fmaf(gv.w, k[dp + 3], tmp);
        }
        acc = fmaf(k[d], A[d] + 0.5f * tmp, acc);
    }
    part[wv][l] = acc;
    __syncthreads();
    if (t < 64) {
        float s = ((part[0][t] + part[1][t]) + part[2][t]) + part[3][t];
        pimp[g * SEQ + jc * 64 + t] = s;
    }
}

// ---- rank: f64 group-sum inline (g-ascending), exact top-k,
//      R15-proven 256-block geometry ----
__global__ __launch_bounds__(256)
void k_rank(const float* __restrict__ pimp, int* __restrict__ sel) {
    __shared__ double v[SEQ];
    for (int j = threadIdx.x; j < SEQ; j += 256) {
        double s = 0.0;
        #pragma unroll
        for (int g = 0; g < 8; ++g) s += (double)pimp[g * SEQ + j];
        v[j] = s;
    }
    __syncthreads();
    const int grp = threadIdx.x >> 5, lane32 = threadIdx.x & 31;
    const int j = blockIdx.x * 8 + grp;
    double vj = v[j];
    int rank = 0;
    #pragma unroll 8
    for (int i = 0; i < 64; ++i) {
        int j2 = i * 32 + lane32;
        double u = v[j2];
        rank += (u > vj || (u == vj && j2 < j)) ? 1 : 0;
    }
    #pragma unroll
    for (int off = 16; off; off >>= 1) rank += __shfl_xor(rank, off, 32);
    if (lane32 == 0) sel[j] = (rank < COMP) ? 1 : 0;
}

// ---- compact + last-slot override + gather ids ----
__global__ __launch_bounds__(256)
void k_out(const int* __restrict__ sel, const int* __restrict__ ids, int* __restrict__ out) {
    __shared__ int s[SEQ];
    __shared__ int part[256];
    int t = threadIdx.x;
    for (int j = t; j < SEQ; j += 256) s[j] = sel[j];
    __syncthreads();
    int base = t * 8, cnt = 0;
    #pragma unroll
    for (int r = 0; r < 8; ++r) cnt += s[base + r];
    part[t] = cnt;
    __syncthreads();
    if (t == 0) {
        int run = 0;
        for (int i2 = 0; i2 < 256; ++i2) { int tmp = part[i2]; part[i2] = run; run += tmp; }
    }
    __syncthreads();
    int pos = part[t];
    for (int r = 0; r < 8; ++r) {
        int j = base + r;
        if (s[j]) {
            int idx = (pos == COMP - 1) ? (SEQ - 1) : j;
            out[COMP + pos] = idx;
            out[pos] = ids[idx];
            pos++;
        }
    }
}

extern "C" void kernel_launch(void* const* d_in, const int* in_sizes, int n_in,
                              void* d_out, int out_size, void* d_ws, size_t ws_size,
                              hipStream_t stream) {
    const int*   ids = (const int*)d_in[0];
    const float* tab = (const float*)d_in[1];
    const float* wq  = (const float*)d_in[2];
    const float* wk  = (const float*)d_in[3];
    const float* ct  = (const float*)d_in[4];
    const float* st  = (const float*)d_in[5];
    int* out = (int*)d_out;
    char* ws = (char*)d_ws;

    const size_t MB = 1 << 20;
    char*  xp    = ws;                                   // 16 MB packed x hi/lo
    char*  wp    = ws + 16 * MB;                         // 20 MB packed W hi/lo
    float* qf    = (float*)(ws + 36 * MB);               // 16 MB [32][2048][64]
    float* kf    = (float*)(ws + 52 * MB);               //  4 MB [8][2048][64]
    float* ksumP = (float*)(ws + 56 * MB);               // 32 KB
    float* Gp    = (float*)(ws + 56 * MB + 0x10000);     //  4 MB [8][32][4096]
    float* Ap    = (float*)(ws + 60 * MB + 0x10000);     // 64 KB
    float* Gs    = (float*)(ws + 60 * MB + 0x20000);     // 128 KB [8][4096]
    float* As    = (float*)(ws + 60 * MB + 0x40000);     //  2 KB
    float* pimp  = (float*)(ws + 60 * MB + 0x50000);     // 64 KB [8][2048]
    int*   sel   = (int*)(ws + 60 * MB + 0x60000);       //  8 KB

    k_split<<<2304, 256, 0, stream>>>(ids, tab, wq, wk, xp, wp);
    k_gemm<<<320, 256, 0, stream>>>(xp, wp, ct, st, qf, kf, ksumP);
    k_moments<<<256, 256, 0, stream>>>(qf, ksumP, Ap, Gp);
    k_gsum<<<128, 256, 0, stream>>>(Gp, Ap, Gs, As);
    k_eval<<<256, 256, 0, stream>>>(kf, As, Gs, pimp);
    k_rank<<<256, 256, 0, stream>>>(pimp, sel);
    k_out<<<1, 256, 0, stream>>>(sel, ids, out);
}